// Round 1
// baseline (5216.755 us; speedup 1.0000x reference)
//
#include <hip/hip_runtime.h>
#include <math.h>

// Sizes: K=4, B=1024, C=128, T=64, D=64, H=4, HD=16, N=B*D=65536
#define EPSV 1e-5f

__device__ __forceinline__ float bcastf(float v, int lane) {
  // wave-uniform broadcast: v_readlane -> SGPR, used as scalar FMA operand
  return __int_as_float(__builtin_amdgcn_readlane(__float_as_int(v), lane));
}

__device__ __forceinline__ float wave_sum64(float v) {
  v += __shfl_xor(v, 1);
  v += __shfl_xor(v, 2);
  v += __shfl_xor(v, 4);
  v += __shfl_xor(v, 8);
  v += __shfl_xor(v, 16);
  v += __shfl_xor(v, 32);
  return v;
}

__device__ __forceinline__ float group16_sum(float v) {
  v += __shfl_xor(v, 1);
  v += __shfl_xor(v, 2);
  v += __shfl_xor(v, 4);
  v += __shfl_xor(v, 8);
  return v;
}

// ---------------------------------------------------------------------------
// Kernel 1: proj[k,b,d,t] = sum_c feats[k,b,c,t]*proj_w[k,d,c] + proj_b[k,d]
// written directly into the reference's reshuffled ctx layout:
//   ctx[n*256 + j*64 + t],  n = b*64 + k*16 + (d>>2),  j = d&3
// One block per (k,b). 256 threads, 4x4 microtile per thread.
// ---------------------------------------------------------------------------
__global__ __launch_bounds__(256, 2) void proj_kernel(
    const float* __restrict__ feats, const float* __restrict__ pw,
    const float* __restrict__ pb, float* __restrict__ ctx) {
  int kb = blockIdx.x;          // kb = k*1024 + b
  int k = kb >> 10;
  int b = kb & 1023;

  __shared__ __align__(16) float F[128 * 64];   // F[c*64 + t]
  __shared__ float W[64 * 129];                 // W[d*129 + c], padded

  const float* fsrc = feats + (size_t)kb * 8192;
  const float* wsrc = pw + k * 8192;
  for (int idx = threadIdx.x; idx < 8192; idx += 256) {
    F[idx] = fsrc[idx];
    W[(idx >> 7) * 129 + (idx & 127)] = wsrc[idx];
  }
  __syncthreads();

  int t4 = threadIdx.x & 15;    // t = t4*4 .. t4*4+3
  int d4 = threadIdx.x >> 4;    // d = d4*4 .. d4*4+3

  float pb0 = pb[k * 64 + d4 * 4 + 0];
  float pb1 = pb[k * 64 + d4 * 4 + 1];
  float pb2 = pb[k * 64 + d4 * 4 + 2];
  float pb3 = pb[k * 64 + d4 * 4 + 3];

  float acc[4][4];
#pragma unroll
  for (int j = 0; j < 4; ++j) {
    acc[0][j] = pb0; acc[1][j] = pb1; acc[2][j] = pb2; acc[3][j] = pb3;
  }

#pragma unroll 8
  for (int c = 0; c < 128; ++c) {
    float4 f = *(const float4*)&F[c * 64 + t4 * 4];
    float w0 = W[(d4 * 4 + 0) * 129 + c];
    float w1 = W[(d4 * 4 + 1) * 129 + c];
    float w2 = W[(d4 * 4 + 2) * 129 + c];
    float w3 = W[(d4 * 4 + 3) * 129 + c];
    acc[0][0] += w0 * f.x; acc[0][1] += w0 * f.y; acc[0][2] += w0 * f.z; acc[0][3] += w0 * f.w;
    acc[1][0] += w1 * f.x; acc[1][1] += w1 * f.y; acc[1][2] += w1 * f.z; acc[1][3] += w1 * f.w;
    acc[2][0] += w2 * f.x; acc[2][1] += w2 * f.y; acc[2][2] += w2 * f.z; acc[2][3] += w2 * f.w;
    acc[3][0] += w3 * f.x; acc[3][1] += w3 * f.y; acc[3][2] += w3 * f.z; acc[3][3] += w3 * f.w;
  }

  // n = b*64 + k*16 + d4 ; j = r (=d&3) ; t = t4*4..+3
  size_t base = ((size_t)b * 64 + k * 16 + d4) * 256 + t4 * 4;
#pragma unroll
  for (int r = 0; r < 4; ++r) {
    float4 o;
    o.x = acc[r][0]; o.y = acc[r][1]; o.z = acc[r][2]; o.w = acc[r][3];
    *(float4*)&ctx[base + r * 64] = o;
  }
}

// ---------------------------------------------------------------------------
// Kernel 2 (templated on module I): per row n:
//   q = ctx[n,I,:] @ wq^T + bq ; k/v = ctx[n,:,:] @ w{k,v}^T + b{k,v}
//   4-key/4-head attention, o @ wo^T + bo, residual + LN, scale by w[I]
//   write into d_out[n*256 + I*64 + d]  (comb layout, pre-final-LN)
// One wave per row; lane = d. Weights transposed in padded LDS.
// ---------------------------------------------------------------------------
template <int I>
__global__ __launch_bounds__(256, 2) void attn_kernel(
    const float* __restrict__ ctx,
    const float* __restrict__ wq, const float* __restrict__ wk,
    const float* __restrict__ wv, const float* __restrict__ wo,
    const float* __restrict__ bq, const float* __restrict__ bk,
    const float* __restrict__ bv, const float* __restrict__ bo,
    const float* __restrict__ ng, const float* __restrict__ nb,
    const float* __restrict__ tfw, float* __restrict__ outbuf) {
  __shared__ float WQT[64 * 65];   // WQT[t*65 + d] = wq[I][d][t]
  __shared__ float WKT[64 * 65];
  __shared__ float WVT[64 * 65];
  __shared__ float WOT[64 * 65];
  __shared__ float BQ[64], BK[64], BV[64], BO[64], NGs[64], NBs[64];

  {
    int t = threadIdx.x & 63;
    int d0 = threadIdx.x >> 6;
    const float* wqb = wq + I * 4096;
    const float* wkb = wk + I * 4096;
    const float* wvb = wv + I * 4096;
    const float* wob = wo + I * 4096;
#pragma unroll
    for (int d = d0; d < 64; d += 4) {
      WQT[t * 65 + d] = wqb[d * 64 + t];
      WKT[t * 65 + d] = wkb[d * 64 + t];
      WVT[t * 65 + d] = wvb[d * 64 + t];
      WOT[t * 65 + d] = wob[d * 64 + t];
    }
    if (threadIdx.x < 64) {
      BQ[t] = bq[I * 64 + t];
      BK[t] = bk[I * 64 + t];
      BV[t] = bv[I * 64 + t];
      BO[t] = bo[I * 64 + t];
      NGs[t] = ng[I * 64 + t];
      NBs[t] = nb[I * 64 + t];
    }
  }

  // w = softmax(tfw)[I] — every thread computes it (4 cached global reads)
  float tf0 = tfw[0], tf1 = tfw[1], tf2 = tfw[2], tf3 = tfw[3];
  float tm = fmaxf(fmaxf(tf0, tf1), fmaxf(tf2, tf3));
  float te0 = __expf(tf0 - tm), te1 = __expf(tf1 - tm);
  float te2 = __expf(tf2 - tm), te3 = __expf(tf3 - tm);
  float wi = ((I == 0) ? te0 : (I == 1) ? te1 : (I == 2) ? te2 : te3) /
             (te0 + te1 + te2 + te3);

  __syncthreads();

  int lane = threadIdx.x & 63;
  int wave = threadIdx.x >> 6;

#pragma unroll 1
  for (int r = 0; r < 8; ++r) {
    int n = blockIdx.x * 32 + wave * 8 + r;
    const float* crow = ctx + (size_t)n * 256;
    float c0 = crow[lane];
    float c1 = crow[64 + lane];
    float c2 = crow[128 + lane];
    float c3 = crow[192 + lane];

    float qa = BQ[lane];
    float bk0 = BK[lane], bv0 = BV[lane];
    float ka0 = bk0, ka1 = bk0, ka2 = bk0, ka3 = bk0;
    float va0 = bv0, va1 = bv0, va2 = bv0, va3 = bv0;

#pragma unroll
    for (int t = 0; t < 64; ++t) {
      float wqv = WQT[t * 65 + lane];
      float wkv = WKT[t * 65 + lane];
      float wvv = WVT[t * 65 + lane];
      float s0 = bcastf(c0, t);
      float s1 = bcastf(c1, t);
      float s2 = bcastf(c2, t);
      float s3 = bcastf(c3, t);
      float si = (I == 0) ? s0 : (I == 1) ? s1 : (I == 2) ? s2 : s3;
      qa += wqv * si;
      ka0 += wkv * s0; ka1 += wkv * s1; ka2 += wkv * s2; ka3 += wkv * s3;
      va0 += wvv * s0; va1 += wvv * s1; va2 += wvv * s2; va3 += wvv * s3;
    }

    // sc[h,kk] = scale * sum_e q[h*16+e]*k[kk][h*16+e] ; scale = 1/sqrt(16)
    float p0 = group16_sum(qa * ka0) * 0.25f;
    float p1 = group16_sum(qa * ka1) * 0.25f;
    float p2 = group16_sum(qa * ka2) * 0.25f;
    float p3 = group16_sum(qa * ka3) * 0.25f;
    float m = fmaxf(fmaxf(p0, p1), fmaxf(p2, p3));
    float a0 = __expf(p0 - m), a1 = __expf(p1 - m);
    float a2 = __expf(p2 - m), a3 = __expf(p3 - m);
    float ainv = 1.0f / (a0 + a1 + a2 + a3);
    float oa = (a0 * va0 + a1 * va1 + a2 * va2 + a3 * va3) * ainv;

    // o2[d] = bo[d] + sum_t wo[d][t] * oa[t]
    float o2 = BO[lane];
#pragma unroll
    for (int t = 0; t < 64; ++t) {
      o2 += WOT[t * 65 + lane] * bcastf(oa, t);
    }

    float qin = (I == 0) ? c0 : (I == 1) ? c1 : (I == 2) ? c2 : c3;
    float rr = o2 + qin;

    // LN over the 64 lanes
    float mean = wave_sum64(rr) * (1.0f / 64.0f);
    float dx = rr - mean;
    float var = wave_sum64(dx * dx) * (1.0f / 64.0f);
    float outv = dx * rsqrtf(var + EPSV) * NGs[lane] + NBs[lane];

    outbuf[(size_t)n * 256 + I * 64 + lane] = wi * outv;
  }
}

// ---------------------------------------------------------------------------
// Kernel 3: final LN over last axis (K*D=256) of fused (B, D, 256), in place.
// One wave per row n; lane holds 4 consecutive values (float4).
// ---------------------------------------------------------------------------
__global__ __launch_bounds__(256, 4) void final_ln_kernel(
    float* __restrict__ out, const float* __restrict__ fg,
    const float* __restrict__ fb) {
  int lane = threadIdx.x & 63;
  int wave = threadIdx.x >> 6;
  size_t n = (size_t)blockIdx.x * 4 + wave;

  float4 v = *(const float4*)&out[n * 256 + lane * 4];
  float mean = wave_sum64(v.x + v.y + v.z + v.w) * (1.0f / 256.0f);
  float dx = v.x - mean, dy = v.y - mean, dz = v.z - mean, dw = v.w - mean;
  float var = wave_sum64(dx * dx + dy * dy + dz * dz + dw * dw) * (1.0f / 256.0f);
  float inv = rsqrtf(var + EPSV);

  float4 g = *(const float4*)&fg[lane * 4];
  float4 bb = *(const float4*)&fb[lane * 4];
  float4 o;
  o.x = dx * inv * g.x + bb.x;
  o.y = dy * inv * g.y + bb.y;
  o.z = dz * inv * g.z + bb.z;
  o.w = dw * inv * g.w + bb.w;
  *(float4*)&out[n * 256 + lane * 4] = o;
}

// ---------------------------------------------------------------------------
extern "C" void kernel_launch(void* const* d_in, const int* in_sizes, int n_in,
                              void* d_out, int out_size, void* d_ws, size_t ws_size,
                              hipStream_t stream) {
  const float* feats  = (const float*)d_in[0];
  const float* proj_w = (const float*)d_in[1];
  const float* proj_b = (const float*)d_in[2];
  const float* wq  = (const float*)d_in[3];
  const float* wk  = (const float*)d_in[4];
  const float* wv  = (const float*)d_in[5];
  const float* bq  = (const float*)d_in[6];
  const float* bk  = (const float*)d_in[7];
  const float* bv  = (const float*)d_in[8];
  const float* wo  = (const float*)d_in[9];
  const float* bo  = (const float*)d_in[10];
  const float* ng  = (const float*)d_in[11];
  const float* nb  = (const float*)d_in[12];
  const float* tfw = (const float*)d_in[13];
  const float* fg  = (const float*)d_in[14];
  const float* fb  = (const float*)d_in[15];
  float* out = (float*)d_out;
  float* ctx = (float*)d_ws;   // 65536 * 256 floats = 64 MB

  // Phase A: projection into reshuffled ctx layout
  proj_kernel<<<4096, 256, 0, stream>>>(feats, proj_w, proj_b, ctx);

  // Phase B/C: fused per-row attention + per-module LN, scaled by softmax(tfw)
  attn_kernel<0><<<2048, 256, 0, stream>>>(ctx, wq, wk, wv, wo, bq, bk, bv, bo, ng, nb, tfw, out);
  attn_kernel<1><<<2048, 256, 0, stream>>>(ctx, wq, wk, wv, wo, bq, bk, bv, bo, ng, nb, tfw, out);
  attn_kernel<2><<<2048, 256, 0, stream>>>(ctx, wq, wk, wv, wo, bq, bk, bv, bo, ng, nb, tfw, out);
  attn_kernel<3><<<2048, 256, 0, stream>>>(ctx, wq, wk, wv, wo, bq, bk, bv, bo, ng, nb, tfw, out);

  // Final LN over K*D=256, in place on d_out
  final_ln_kernel<<<16384, 256, 0, stream>>>(out, fg, fb);
}

// Round 2
// 813.815 us; speedup vs baseline: 6.4102x; 6.4102x over previous
//
#include <hip/hip_runtime.h>
#include <math.h>

// Sizes: K=4, B=1024, C=128, T=64, D=64, H=4, HD=16, N=B*D=65536
#define EPSV 1e-5f

__device__ __forceinline__ float bcastf(float v, int lane) {
  // wave-uniform broadcast: v_readlane -> SGPR, used as scalar FMA operand
  return __int_as_float(__builtin_amdgcn_readlane(__float_as_int(v), lane));
}

__device__ __forceinline__ float wave_sum64(float v) {
  v += __shfl_xor(v, 1);
  v += __shfl_xor(v, 2);
  v += __shfl_xor(v, 4);
  v += __shfl_xor(v, 8);
  v += __shfl_xor(v, 16);
  v += __shfl_xor(v, 32);
  return v;
}

__device__ __forceinline__ float group16_sum(float v) {
  v += __shfl_xor(v, 1);
  v += __shfl_xor(v, 2);
  v += __shfl_xor(v, 4);
  v += __shfl_xor(v, 8);
  return v;
}

// ---------------------------------------------------------------------------
// Kernel 1: proj[k,b,d,t] = sum_c feats[k,b,c,t]*proj_w[k,d,c] + proj_b[k,d]
// written directly into the reference's reshuffled ctx layout:
//   ctx[n*256 + j*64 + t],  n = b*64 + k*16 + (d>>2),  j = d&3
// One block per (k,b). 256 threads, 4x4 microtile per thread.
// ---------------------------------------------------------------------------
__global__ __launch_bounds__(256, 2) void proj_kernel(
    const float* __restrict__ feats, const float* __restrict__ pw,
    const float* __restrict__ pb, float* __restrict__ ctx) {
  int kb = blockIdx.x;          // kb = k*1024 + b
  int k = kb >> 10;
  int b = kb & 1023;

  __shared__ __align__(16) float F[128 * 64];   // F[c*64 + t]
  __shared__ float W[64 * 129];                 // W[d*129 + c], padded

  const float* fsrc = feats + (size_t)kb * 8192;
  const float* wsrc = pw + k * 8192;
  for (int idx = threadIdx.x; idx < 8192; idx += 256) {
    F[idx] = fsrc[idx];
    W[(idx >> 7) * 129 + (idx & 127)] = wsrc[idx];
  }
  __syncthreads();

  int t4 = threadIdx.x & 15;    // t = t4*4 .. t4*4+3
  int d4 = threadIdx.x >> 4;    // d = d4*4 .. d4*4+3

  float pb0 = pb[k * 64 + d4 * 4 + 0];
  float pb1 = pb[k * 64 + d4 * 4 + 1];
  float pb2 = pb[k * 64 + d4 * 4 + 2];
  float pb3 = pb[k * 64 + d4 * 4 + 3];

  float acc[4][4];
#pragma unroll
  for (int j = 0; j < 4; ++j) {
    acc[0][j] = pb0; acc[1][j] = pb1; acc[2][j] = pb2; acc[3][j] = pb3;
  }

#pragma unroll 8
  for (int c = 0; c < 128; ++c) {
    float4 f = *(const float4*)&F[c * 64 + t4 * 4];
    float w0 = W[(d4 * 4 + 0) * 129 + c];
    float w1 = W[(d4 * 4 + 1) * 129 + c];
    float w2 = W[(d4 * 4 + 2) * 129 + c];
    float w3 = W[(d4 * 4 + 3) * 129 + c];
    acc[0][0] += w0 * f.x; acc[0][1] += w0 * f.y; acc[0][2] += w0 * f.z; acc[0][3] += w0 * f.w;
    acc[1][0] += w1 * f.x; acc[1][1] += w1 * f.y; acc[1][2] += w1 * f.z; acc[1][3] += w1 * f.w;
    acc[2][0] += w2 * f.x; acc[2][1] += w2 * f.y; acc[2][2] += w2 * f.z; acc[2][3] += w2 * f.w;
    acc[3][0] += w3 * f.x; acc[3][1] += w3 * f.y; acc[3][2] += w3 * f.z; acc[3][3] += w3 * f.w;
  }

  // n = b*64 + k*16 + d4 ; j = r (=d&3) ; t = t4*4..+3
  size_t base = ((size_t)b * 64 + k * 16 + d4) * 256 + t4 * 4;
#pragma unroll
  for (int r = 0; r < 4; ++r) {
    float4 o;
    o.x = acc[r][0]; o.y = acc[r][1]; o.z = acc[r][2]; o.w = acc[r][3];
    *(float4*)&ctx[base + r * 64] = o;
  }
}

// ---------------------------------------------------------------------------
// Kernel 2 (templated on module I): per row n:
//   q = ctx[n,I,:] @ wq^T + bq ; k/v = ctx[n,:,:] @ w{k,v}^T + b{k,v}
//   4-key/4-head attention, o @ wo^T + bo, residual + LN, scale by w[I]
//   write into d_out[n*256 + I*64 + d]  (comb layout, pre-final-LN)
//
// 512 threads = 8 waves/block; each wave handles 8 rows in 2 batches of 4.
// Weights transposed into padded LDS (conflict-free both ways).
// t-loops kept as real loops (unroll 4) — full unroll blew L1I and caused
// 1.9 GB/dispatch of instruction refetch from L2/HBM (round-1 lesson).
// ---------------------------------------------------------------------------
template <int I>
__global__ __launch_bounds__(512, 4) void attn_kernel(
    const float* __restrict__ ctx,
    const float* __restrict__ wq, const float* __restrict__ wk,
    const float* __restrict__ wv, const float* __restrict__ wo,
    const float* __restrict__ bq, const float* __restrict__ bk,
    const float* __restrict__ bv, const float* __restrict__ bo,
    const float* __restrict__ ng, const float* __restrict__ nb,
    const float* __restrict__ tfw, float* __restrict__ outbuf) {
  __shared__ float WQT[64 * 65];   // WQT[t*65 + d] = wq[I][d][t]
  __shared__ float WKT[64 * 65];
  __shared__ float WVT[64 * 65];
  __shared__ float WOT[64 * 65];
  __shared__ float BQ[64], BK[64], BV[64], BO[64], NGs[64], NBs[64];

  {
    int t = threadIdx.x & 63;
    int d0 = threadIdx.x >> 6;   // 0..7
    const float* wqb = wq + I * 4096;
    const float* wkb = wk + I * 4096;
    const float* wvb = wv + I * 4096;
    const float* wob = wo + I * 4096;
    for (int d = d0; d < 64; d += 8) {
      WQT[t * 65 + d] = wqb[d * 64 + t];
      WKT[t * 65 + d] = wkb[d * 64 + t];
      WVT[t * 65 + d] = wvb[d * 64 + t];
      WOT[t * 65 + d] = wob[d * 64 + t];
    }
    if (threadIdx.x < 64) {
      BQ[t] = bq[I * 64 + t];
      BK[t] = bk[I * 64 + t];
      BV[t] = bv[I * 64 + t];
      BO[t] = bo[I * 64 + t];
      NGs[t] = ng[I * 64 + t];
      NBs[t] = nb[I * 64 + t];
    }
  }

  // w = softmax(tfw)[I]
  float tf0 = tfw[0], tf1 = tfw[1], tf2 = tfw[2], tf3 = tfw[3];
  float tm = fmaxf(fmaxf(tf0, tf1), fmaxf(tf2, tf3));
  float te0 = __expf(tf0 - tm), te1 = __expf(tf1 - tm);
  float te2 = __expf(tf2 - tm), te3 = __expf(tf3 - tm);
  float wi = ((I == 0) ? te0 : (I == 1) ? te1 : (I == 2) ? te2 : te3) /
             (te0 + te1 + te2 + te3);

  __syncthreads();

  int lane = threadIdx.x & 63;
  int wave = threadIdx.x >> 6;                // 0..7
  int wave_id = blockIdx.x * 8 + wave;        // 0..8191
  int row_base = wave_id * 8;                 // 8 rows per wave

  float bq0 = BQ[lane], bk0 = BK[lane], bv0 = BV[lane], bo0 = BO[lane];
  float ngv = NGs[lane], nbv = NBs[lane];

#pragma unroll 1
  for (int batch = 0; batch < 2; ++batch) {
    int n0 = row_base + batch * 4;

    // Load 4 rows' ctx segments: c[r][j] = ctx[(n0+r)*256 + j*64 + lane]
    float c[4][4];
#pragma unroll
    for (int r = 0; r < 4; ++r) {
      const float* crow = ctx + (size_t)(n0 + r) * 256;
      c[r][0] = crow[lane];
      c[r][1] = crow[64 + lane];
      c[r][2] = crow[128 + lane];
      c[r][3] = crow[192 + lane];
    }

    float qa[4], ka[4][4], va[4][4];
#pragma unroll
    for (int r = 0; r < 4; ++r) {
      qa[r] = bq0;
#pragma unroll
      for (int j = 0; j < 4; ++j) { ka[r][j] = bk0; va[r][j] = bv0; }
    }

#pragma unroll 4
    for (int t = 0; t < 64; ++t) {
      float wqv = WQT[t * 65 + lane];
      float wkv = WKT[t * 65 + lane];
      float wvv = WVT[t * 65 + lane];
#pragma unroll
      for (int r = 0; r < 4; ++r) {
        float s0 = bcastf(c[r][0], t);
        float s1 = bcastf(c[r][1], t);
        float s2 = bcastf(c[r][2], t);
        float s3 = bcastf(c[r][3], t);
        float si = (I == 0) ? s0 : (I == 1) ? s1 : (I == 2) ? s2 : s3;
        qa[r] += wqv * si;
        ka[r][0] += wkv * s0; ka[r][1] += wkv * s1;
        ka[r][2] += wkv * s2; ka[r][3] += wkv * s3;
        va[r][0] += wvv * s0; va[r][1] += wvv * s1;
        va[r][2] += wvv * s2; va[r][3] += wvv * s3;
      }
    }

    // Attention per row: sc[h,kk] = 0.25 * sum_{e in head h} q*k
    float oa[4];
#pragma unroll
    for (int r = 0; r < 4; ++r) {
      float p0 = group16_sum(qa[r] * ka[r][0]) * 0.25f;
      float p1 = group16_sum(qa[r] * ka[r][1]) * 0.25f;
      float p2 = group16_sum(qa[r] * ka[r][2]) * 0.25f;
      float p3 = group16_sum(qa[r] * ka[r][3]) * 0.25f;
      float m = fmaxf(fmaxf(p0, p1), fmaxf(p2, p3));
      float a0 = __expf(p0 - m), a1 = __expf(p1 - m);
      float a2 = __expf(p2 - m), a3 = __expf(p3 - m);
      float ainv = 1.0f / (a0 + a1 + a2 + a3);
      oa[r] = (a0 * va[r][0] + a1 * va[r][1] + a2 * va[r][2] + a3 * va[r][3]) * ainv;
    }

    // o2[d] = bo[d] + sum_t wo[d][t] * oa[t]
    float o2[4] = {bo0, bo0, bo0, bo0};
#pragma unroll 8
    for (int t = 0; t < 64; ++t) {
      float wov = WOT[t * 65 + lane];
      o2[0] += wov * bcastf(oa[0], t);
      o2[1] += wov * bcastf(oa[1], t);
      o2[2] += wov * bcastf(oa[2], t);
      o2[3] += wov * bcastf(oa[3], t);
    }

    // Residual + LN + scale + store
#pragma unroll
    for (int r = 0; r < 4; ++r) {
      float rr = o2[r] + c[r][I];
      float mean = wave_sum64(rr) * (1.0f / 64.0f);
      float dx = rr - mean;
      float var = wave_sum64(dx * dx) * (1.0f / 64.0f);
      float outv = dx * rsqrtf(var + EPSV) * ngv + nbv;
      outbuf[(size_t)(n0 + r) * 256 + I * 64 + lane] = wi * outv;
    }
  }
}

// ---------------------------------------------------------------------------
// Kernel 3: final LN over last axis (K*D=256) of fused (B, D, 256), in place.
// ---------------------------------------------------------------------------
__global__ __launch_bounds__(256, 4) void final_ln_kernel(
    float* __restrict__ out, const float* __restrict__ fg,
    const float* __restrict__ fb) {
  int lane = threadIdx.x & 63;
  int wave = threadIdx.x >> 6;
  size_t n = (size_t)blockIdx.x * 4 + wave;

  float4 v = *(const float4*)&out[n * 256 + lane * 4];
  float mean = wave_sum64(v.x + v.y + v.z + v.w) * (1.0f / 256.0f);
  float dx = v.x - mean, dy = v.y - mean, dz = v.z - mean, dw = v.w - mean;
  float var = wave_sum64(dx * dx + dy * dy + dz * dz + dw * dw) * (1.0f / 256.0f);
  float inv = rsqrtf(var + EPSV);

  float4 g = *(const float4*)&fg[lane * 4];
  float4 bb = *(const float4*)&fb[lane * 4];
  float4 o;
  o.x = dx * inv * g.x + bb.x;
  o.y = dy * inv * g.y + bb.y;
  o.z = dz * inv * g.z + bb.z;
  o.w = dw * inv * g.w + bb.w;
  *(float4*)&out[n * 256 + lane * 4] = o;
}

// ---------------------------------------------------------------------------
extern "C" void kernel_launch(void* const* d_in, const int* in_sizes, int n_in,
                              void* d_out, int out_size, void* d_ws, size_t ws_size,
                              hipStream_t stream) {
  const float* feats  = (const float*)d_in[0];
  const float* proj_w = (const float*)d_in[1];
  const float* proj_b = (const float*)d_in[2];
  const float* wq  = (const float*)d_in[3];
  const float* wk  = (const float*)d_in[4];
  const float* wv  = (const float*)d_in[5];
  const float* bq  = (const float*)d_in[6];
  const float* bk  = (const float*)d_in[7];
  const float* bv  = (const float*)d_in[8];
  const float* wo  = (const float*)d_in[9];
  const float* bo  = (const float*)d_in[10];
  const float* ng  = (const float*)d_in[11];
  const float* nb  = (const float*)d_in[12];
  const float* tfw = (const float*)d_in[13];
  const float* fg  = (const float*)d_in[14];
  const float* fb  = (const float*)d_in[15];
  float* out = (float*)d_out;
  float* ctx = (float*)d_ws;   // 65536 * 256 floats = 64 MB

  // Phase A: projection into reshuffled ctx layout
  proj_kernel<<<4096, 256, 0, stream>>>(feats, proj_w, proj_b, ctx);

  // Phase B/C: per-module fused attention + per-module LN, scaled by softmax(tfw)
  attn_kernel<0><<<1024, 512, 0, stream>>>(ctx, wq, wk, wv, wo, bq, bk, bv, bo, ng, nb, tfw, out);
  attn_kernel<1><<<1024, 512, 0, stream>>>(ctx, wq, wk, wv, wo, bq, bk, bv, bo, ng, nb, tfw, out);
  attn_kernel<2><<<1024, 512, 0, stream>>>(ctx, wq, wk, wv, wo, bq, bk, bv, bo, ng, nb, tfw, out);
  attn_kernel<3><<<1024, 512, 0, stream>>>(ctx, wq, wk, wv, wo, bq, bk, bv, bo, ng, nb, tfw, out);

  // Final LN over K*D=256, in place on d_out
  final_ln_kernel<<<16384, 256, 0, stream>>>(out, fg, fb);
}

// Round 4
// 423.468 us; speedup vs baseline: 12.3191x; 1.9218x over previous
//
#include <hip/hip_runtime.h>
#include <math.h>

// Sizes: K=4, B=1024, C=128, T=64, D=64, H=4, HD=16, N=B*D=65536
#define EPSV 1e-5f

typedef __attribute__((ext_vector_type(8))) short short8;   // 8 x bf16 (4 VGPRs)
typedef __attribute__((ext_vector_type(4))) float float4v;  // MFMA 16x16 acc

__device__ __forceinline__ unsigned short f2bf(float f) {   // fp32 -> bf16 RNE
  unsigned int x = __float_as_uint(f);
  return (unsigned short)((x + 0x7fffu + ((x >> 16) & 1u)) >> 16);
}
__device__ __forceinline__ float bf2f(unsigned short u) {
  return __uint_as_float(((unsigned int)u) << 16);
}
__device__ __forceinline__ float wave_sum64(float v) {
  v += __shfl_xor(v, 1);
  v += __shfl_xor(v, 2);
  v += __shfl_xor(v, 4);
  v += __shfl_xor(v, 8);
  v += __shfl_xor(v, 16);
  v += __shfl_xor(v, 32);
  return v;
}
__device__ __forceinline__ float group16_sum(float v) {     // sum over lane&15 group
  v += __shfl_xor(v, 1);
  v += __shfl_xor(v, 2);
  v += __shfl_xor(v, 4);
  v += __shfl_xor(v, 8);
  return v;
}

// ---------------------------------------------------------------------------
// Kernel 1 (round-2 proven, unchanged): proj -> plain fp32 ctx:
//   ctx[n*256 + j*64 + t],  n = b*64 + k*16 + (d>>2),  j = d&3
// ---------------------------------------------------------------------------
__global__ __launch_bounds__(256, 2) void proj_kernel(
    const float* __restrict__ feats, const float* __restrict__ pw,
    const float* __restrict__ pb, float* __restrict__ ctx) {
  int kb = blockIdx.x;          // kb = k*1024 + b
  int k = kb >> 10;
  int b = kb & 1023;

  __shared__ __align__(16) float F[128 * 64];   // F[c*64 + t]
  __shared__ float W[64 * 129];                 // W[d*129 + c], padded

  const float* fsrc = feats + (size_t)kb * 8192;
  const float* wsrc = pw + k * 8192;
  for (int idx = threadIdx.x; idx < 8192; idx += 256) {
    F[idx] = fsrc[idx];
    W[(idx >> 7) * 129 + (idx & 127)] = wsrc[idx];
  }
  __syncthreads();

  int t4 = threadIdx.x & 15;    // t = t4*4 .. t4*4+3
  int d4 = threadIdx.x >> 4;    // d = d4*4 .. d4*4+3

  float pb0 = pb[k * 64 + d4 * 4 + 0];
  float pb1 = pb[k * 64 + d4 * 4 + 1];
  float pb2 = pb[k * 64 + d4 * 4 + 2];
  float pb3 = pb[k * 64 + d4 * 4 + 3];

  float acc[4][4];
#pragma unroll
  for (int j = 0; j < 4; ++j) {
    acc[0][j] = pb0; acc[1][j] = pb1; acc[2][j] = pb2; acc[3][j] = pb3;
  }

#pragma unroll 8
  for (int c = 0; c < 128; ++c) {
    float4 f = *(const float4*)&F[c * 64 + t4 * 4];
    float w0 = W[(d4 * 4 + 0) * 129 + c];
    float w1 = W[(d4 * 4 + 1) * 129 + c];
    float w2 = W[(d4 * 4 + 2) * 129 + c];
    float w3 = W[(d4 * 4 + 3) * 129 + c];
    acc[0][0] += w0 * f.x; acc[0][1] += w0 * f.y; acc[0][2] += w0 * f.z; acc[0][3] += w0 * f.w;
    acc[1][0] += w1 * f.x; acc[1][1] += w1 * f.y; acc[1][2] += w1 * f.z; acc[1][3] += w1 * f.w;
    acc[2][0] += w2 * f.x; acc[2][1] += w2 * f.y; acc[2][2] += w2 * f.z; acc[2][3] += w2 * f.w;
    acc[3][0] += w3 * f.x; acc[3][1] += w3 * f.y; acc[3][2] += w3 * f.z; acc[3][3] += w3 * f.w;
  }

  size_t base = ((size_t)b * 64 + k * 16 + d4) * 256 + t4 * 4;
#pragma unroll
  for (int r = 0; r < 4; ++r) {
    float4 o;
    o.x = acc[r][0]; o.y = acc[r][1]; o.z = acc[r][2]; o.w = acc[r][3];
    *(float4*)&ctx[base + r * 64] = o;
  }
}

// ---------------------------------------------------------------------------
// Kernel 2: MFMA attention, transparent layouts.
// Block = 4 waves; wave w owns rows n = blockIdx.x*64 + w*16 + 0..15.
// All LDS buffers are PLAIN row-major (padded); MFMA fragments are single
// aligned 16B reads computed directly from the layout definitions:
//   A: lane holds A[m=l&15][k = s*32 + (l>>4)*8 + jj]
//   B: lane holds B[k = s*32 + (l>>4)*8 + jj][n = nt*16 + (l&15)], B[k][n]=w[n][k]
//   C/D: value (lane,reg r) = D[m=(l>>4)*4+r][n = nt*16 + (l&15)]
// Per-module output written to out (comb layout); final LN is a separate pass.
// ---------------------------------------------------------------------------
__global__ __launch_bounds__(256, 2) void attn_fused(
    const float* __restrict__ ctx32,
    const float* __restrict__ wq, const float* __restrict__ wk,
    const float* __restrict__ wv, const float* __restrict__ wo,
    const float* __restrict__ bq, const float* __restrict__ bk,
    const float* __restrict__ bv, const float* __restrict__ bo,
    const float* __restrict__ ng, const float* __restrict__ nb,
    const float* __restrict__ tfw, float* __restrict__ out) {
  __shared__ __align__(16) unsigned short CTP[64 * 264];   // ctx rows, bf16, pad 256->264
  __shared__ __align__(16) unsigned short WBB[4][64 * 72]; // module's wq/wk/wv/wo, pad 64->72
  __shared__ __align__(16) unsigned short OSP[4][16 * 72]; // per-wave o slab [m][d]

  int tid = threadIdx.x;
  int w = tid >> 6, l = tid & 63;
  int l15 = l & 15, lq = l >> 4;

  // stage ctx rows (plain, coalesced fp32 reads -> bf16)
  const float* csrc = ctx32 + (size_t)blockIdx.x * 16384;
  for (int e = tid; e < 16384; e += 256)
    CTP[(e >> 8) * 264 + (e & 255)] = f2bf(csrc[e]);

  // softmax(tfw)
  float tf0 = tfw[0], tf1 = tfw[1], tf2 = tfw[2], tf3 = tfw[3];
  float tm = fmaxf(fmaxf(tf0, tf1), fmaxf(tf2, tf3));
  float te0 = __expf(tf0 - tm), te1 = __expf(tf1 - tm);
  float te2 = __expf(tf2 - tm), te3 = __expf(tf3 - tm);
  float tden = te0 + te1 + te2 + te3;

  const unsigned short* arow = &CTP[(w * 16 + l15) * 264];  // this lane's A row (m = l&15)
  const float4v zf = {0.0f, 0.0f, 0.0f, 0.0f};

#pragma unroll 1
  for (int i = 0; i < 4; ++i) {
    __syncthreads();   // WBB/OSP reads of prev iter done; CTP staged (iter 0)
    {
      const float* s0p = wq + i * 4096;
      const float* s1p = wk + i * 4096;
      const float* s2p = wv + i * 4096;
      const float* s3p = wo + i * 4096;
      for (int e = tid; e < 16384; e += 256) {
        int m = e >> 12, d = (e >> 6) & 63, t = e & 63;
        const float* sp = (m == 0) ? s0p : (m == 1) ? s1p : (m == 2) ? s2p : s3p;
        WBB[m][d * 72 + t] = f2bf(sp[d * 64 + t]);
      }
    }
    __syncthreads();

    float wi = ((i == 0) ? te0 : (i == 1) ? te1 : (i == 2) ? te2 : te3) / tden;

    float bqv[4], bkv[4], bvv[4], bov[4], ngv[4], nbv[4];
#pragma unroll
    for (int nt = 0; nt < 4; ++nt) {
      int d = i * 64 + nt * 16 + l15;
      bqv[nt] = bq[d]; bkv[nt] = bk[d]; bvv[nt] = bv[d];
      bov[nt] = bo[d]; ngv[nt] = ng[d]; nbv[nt] = nb[d];
    }

    // ---- q = ctx[:,i] @ wq^T + bq ----
    float4v qacc[4] = {zf, zf, zf, zf};
#pragma unroll
    for (int s = 0; s < 2; ++s) {
      short8 af = *(const short8*)&arow[i * 64 + s * 32 + lq * 8];
#pragma unroll
      for (int nt = 0; nt < 4; ++nt) {
        short8 bf = *(const short8*)&WBB[0][(nt * 16 + l15) * 72 + s * 32 + lq * 8];
        qacc[nt] = __builtin_amdgcn_mfma_f32_16x16x32_bf16(af, bf, qacc[nt], 0, 0, 0);
      }
    }
#pragma unroll
    for (int nt = 0; nt < 4; ++nt)
#pragma unroll
      for (int r = 0; r < 4; ++r) qacc[nt][r] += bqv[nt];

    // ---- per key j: k/v GEMMs, scores, un-normalized softmax-weighted V ----
    float4v oacc[4] = {zf, zf, zf, zf};
    float lsum[4][4] = {{0,0,0,0},{0,0,0,0},{0,0,0,0},{0,0,0,0}};

#pragma unroll 1
    for (int j = 0; j < 4; ++j) {
      float4v kacc[4] = {zf, zf, zf, zf};
      float4v vacc[4] = {zf, zf, zf, zf};
#pragma unroll
      for (int s = 0; s < 2; ++s) {
        short8 af = *(const short8*)&arow[j * 64 + s * 32 + lq * 8];
#pragma unroll
        for (int nt = 0; nt < 4; ++nt) {
          short8 bfk = *(const short8*)&WBB[1][(nt * 16 + l15) * 72 + s * 32 + lq * 8];
          short8 bfv = *(const short8*)&WBB[2][(nt * 16 + l15) * 72 + s * 32 + lq * 8];
          kacc[nt] = __builtin_amdgcn_mfma_f32_16x16x32_bf16(af, bfk, kacc[nt], 0, 0, 0);
          vacc[nt] = __builtin_amdgcn_mfma_f32_16x16x32_bf16(af, bfv, vacc[nt], 0, 0, 0);
        }
      }
      // head h == tile nt (HD=16): reduce q*k over e = l&15 within the 16-lane group
#pragma unroll
      for (int nt = 0; nt < 4; ++nt)
#pragma unroll
        for (int r = 0; r < 4; ++r) {
          float p = qacc[nt][r] * (kacc[nt][r] + bkv[nt]);
          p = group16_sum(p) * 0.25f;          // 1/sqrt(HD); |p| small -> no max-sub
          float e = __expf(p);
          lsum[nt][r] += e;
          oacc[nt][r] += e * (vacc[nt][r] + bvv[nt]);
        }
    }

    // ---- o (C/D layout) -> plain [m][d] slab ----
#pragma unroll
    for (int nt = 0; nt < 4; ++nt)
#pragma unroll
      for (int r = 0; r < 4; ++r) {
        float ov = oacc[nt][r] / lsum[nt][r];
        OSP[w][(lq * 4 + r) * 72 + nt * 16 + l15] = f2bf(ov);
      }
    __syncthreads();

    // ---- o2 = o @ wo^T ----
    float4v o2[4] = {zf, zf, zf, zf};
#pragma unroll
    for (int s = 0; s < 2; ++s) {
      short8 af = *(const short8*)&OSP[w][l15 * 72 + s * 32 + lq * 8];
#pragma unroll
      for (int nt = 0; nt < 4; ++nt) {
        short8 bf = *(const short8*)&WBB[3][(nt * 16 + l15) * 72 + s * 32 + lq * 8];
        o2[nt] = __builtin_amdgcn_mfma_f32_16x16x32_bf16(af, bf, o2[nt], 0, 0, 0);
      }
    }

    // ---- + bo + residual (plain CTP read) ----
    float rr[4][4];
#pragma unroll
    for (int nt = 0; nt < 4; ++nt)
#pragma unroll
      for (int r = 0; r < 4; ++r) {
        float qin = bf2f(CTP[(w * 16 + lq * 4 + r) * 264 + i * 64 + nt * 16 + l15]);
        rr[nt][r] = o2[nt][r] + bov[nt] + qin;
      }

    // ---- per-module LN over 64 dims of row m = lq*4+r; scale by wi; store ----
#pragma unroll
    for (int r = 0; r < 4; ++r) {
      float sm = group16_sum(rr[0][r] + rr[1][r] + rr[2][r] + rr[3][r]) * (1.0f / 64.0f);
      float vs = 0.0f;
#pragma unroll
      for (int nt = 0; nt < 4; ++nt) { float dx = rr[nt][r] - sm; vs += dx * dx; }
      vs = group16_sum(vs) * (1.0f / 64.0f);
      float inv = rsqrtf(vs + EPSV);
      size_t row = (size_t)blockIdx.x * 64 + w * 16 + lq * 4 + r;
#pragma unroll
      for (int nt = 0; nt < 4; ++nt) {
        float val = wi * ((rr[nt][r] - sm) * inv * ngv[nt] + nbv[nt]);
        out[row * 256 + i * 64 + nt * 16 + l15] = val;
      }
    }
  }
}

// ---------------------------------------------------------------------------
// Kernel 3 (round-2 proven, unchanged): final LN over K*D=256, in place.
// ---------------------------------------------------------------------------
__global__ __launch_bounds__(256, 4) void final_ln_kernel(
    float* __restrict__ out, const float* __restrict__ fg,
    const float* __restrict__ fb) {
  int lane = threadIdx.x & 63;
  int wave = threadIdx.x >> 6;
  size_t n = (size_t)blockIdx.x * 4 + wave;

  float4 v = *(const float4*)&out[n * 256 + lane * 4];
  float mean = wave_sum64(v.x + v.y + v.z + v.w) * (1.0f / 256.0f);
  float dx = v.x - mean, dy = v.y - mean, dz = v.z - mean, dw = v.w - mean;
  float var = wave_sum64(dx * dx + dy * dy + dz * dz + dw * dw) * (1.0f / 256.0f);
  float inv = rsqrtf(var + EPSV);

  float4 g = *(const float4*)&fg[lane * 4];
  float4 bb = *(const float4*)&fb[lane * 4];
  float4 o;
  o.x = dx * inv * g.x + bb.x;
  o.y = dy * inv * g.y + bb.y;
  o.z = dz * inv * g.z + bb.z;
  o.w = dw * inv * g.w + bb.w;
  *(float4*)&out[n * 256 + lane * 4] = o;
}

// ---------------------------------------------------------------------------
extern "C" void kernel_launch(void* const* d_in, const int* in_sizes, int n_in,
                              void* d_out, int out_size, void* d_ws, size_t ws_size,
                              hipStream_t stream) {
  const float* feats  = (const float*)d_in[0];
  const float* proj_w = (const float*)d_in[1];
  const float* proj_b = (const float*)d_in[2];
  const float* wq  = (const float*)d_in[3];
  const float* wk  = (const float*)d_in[4];
  const float* wv  = (const float*)d_in[5];
  const float* bq  = (const float*)d_in[6];
  const float* bk  = (const float*)d_in[7];
  const float* bv  = (const float*)d_in[8];
  const float* wo  = (const float*)d_in[9];
  const float* bo  = (const float*)d_in[10];
  const float* ng  = (const float*)d_in[11];
  const float* nb  = (const float*)d_in[12];
  const float* tfw = (const float*)d_in[13];
  const float* fg  = (const float*)d_in[14];
  const float* fb  = (const float*)d_in[15];
  float* out = (float*)d_out;
  float* ctx = (float*)d_ws;   // 65536 * 256 floats = 64 MB

  proj_kernel<<<4096, 256, 0, stream>>>(feats, proj_w, proj_b, ctx);
  attn_fused<<<1024, 256, 0, stream>>>(ctx, wq, wk, wv, wo, bq, bk, bv, bo,
                                       ng, nb, tfw, out);
  final_ln_kernel<<<16384, 256, 0, stream>>>(out, fg, fb);
}